// Round 1
// baseline (90.895 us; speedup 1.0000x reference)
//
#include <hip/hip_runtime.h>
#include <math.h>

#define N_   1024
#define IN_  512
#define OUT_ 256
#define E_   3

// ---------------------------------------------------------------------------
// Kernel A: per output node o, pick the operator p = argmax_p(logit + gumbel).
// Store opidx, sign s (+1 for T-norm/min, -1 for T-conorm/max) and the
// no-edge neutral value (1 for T-norm, 0 for T-conorm).
// ---------------------------------------------------------------------------
__global__ __launch_bounds__(256) void setup_op_kernel(
        const float* __restrict__ op_logits,  // [OUT, 2]
        const float* __restrict__ u_op,       // [OUT, 2]
        int*   __restrict__ opidx,            // [OUT]
        float* __restrict__ signv,            // [OUT]
        float* __restrict__ neutral) {        // [OUT]
    int o = threadIdx.x;
    float s0 = op_logits[o * 2 + 0] - logf(-logf(u_op[o * 2 + 0]));
    float s1 = op_logits[o * 2 + 1] - logf(-logf(u_op[o * 2 + 1]));
    int p = (s1 > s0) ? 1 : 0;           // first index wins ties, like jnp.argmax
    opidx[o] = p;
    signv[o] = (p == 0) ? 1.0f : -1.0f;
    neutral[o] = (p == 0) ? 1.0f : 0.0f;
}

// ---------------------------------------------------------------------------
// Kernel B: per (o, i), pick winning edge type e* at p = opidx[o], then store
// packed bf16 coefficients (a, b) such that  s * edge_value = a * x + b.
//   e*=0 (identity):   val = x      -> a =  s, b = 0
//   e*=1 (complement): val = 1 - x  -> a = -s, b = s
//   e*=2 (no_edge):    val = neutral-> a =  0, b = s * neutral
// All coefficient values are in {0, ±1} -> exactly representable in bf16.
// Layout coefT[i][o] so the main kernel's per-step load is coalesced.
// ---------------------------------------------------------------------------
__global__ __launch_bounds__(256) void setup_coef_kernel(
        const float* __restrict__ edge_logits,  // [OUT, 2, IN, 3]
        const float* __restrict__ u_edge,       // [OUT, 2, IN, 3]
        const int*   __restrict__ opidx,
        const float* __restrict__ signv,
        const float* __restrict__ neutral,
        unsigned int* __restrict__ coefT) {     // [IN, OUT] packed bf16x2
    int o = threadIdx.x;   // 256 threads
    int i = blockIdx.x;    // IN_ blocks
    int p = opidx[o];
    long base = (((long)(o * 2 + p)) * IN_ + i) * E_;

    float best = -1e30f;
    int be = 0;
#pragma unroll
    for (int e = 0; e < E_; ++e) {
        float u = u_edge[base + e];
        float sc = edge_logits[base + e] - logf(-logf(u));
        if (sc > best) { best = sc; be = e; }
    }
    float s = signv[o];
    float a, b;
    if (be == 0)      { a = s;    b = 0.0f; }
    else if (be == 1) { a = -s;   b = s;    }
    else              { a = 0.0f; b = s * neutral[o]; }

    unsigned int ua = (__float_as_uint(a) >> 16);
    unsigned int ub = (__float_as_uint(b) & 0xffff0000u);
    coefT[i * OUT_ + o] = ua | ub;
}

// ---------------------------------------------------------------------------
// Kernel C: main reduction. One thread per output node o (256 threads/block),
// NPB consecutive n-rows per block, I split into IN_/ISTEPS chunks.
// x tile staged in LDS transposed [ii][r] so the inner loop reads it with two
// wave-uniform (broadcast, conflict-free) ds_read_b128.
// acc[r] = min over i of (a*x+b); neutral init 2.0 (> any |val| <= 1).
// ---------------------------------------------------------------------------
template <int NPB, int ISTEPS>
__global__ __launch_bounds__(256) void main_kernel(
        const float* __restrict__ x,            // [N, IN]
        const unsigned int* __restrict__ coefT, // [IN, OUT]
        const float* __restrict__ signv,        // [OUT]
        float* __restrict__ outp,               // partial [NSPLIT,N,OUT] or out [N,OUT]
        int write_final) {
    constexpr int NSPLIT = IN_ / ISTEPS;
    int tid = threadIdx.x;
    int bid = blockIdx.x;
    int ks = bid % NSPLIT;
    int nt = bid / NSPLIT;
    int n0 = nt * NPB;
    int i0 = ks * ISTEPS;

    __shared__ float xT[ISTEPS * NPB];

    // cooperative transpose-stage: coalesced global reads
    for (int k = tid; k < ISTEPS * NPB; k += 256) {
        int r = k / ISTEPS;       // compile-time shift
        int ii = k % ISTEPS;
        xT[ii * NPB + r] = x[(n0 + r) * IN_ + i0 + ii];
    }
    __syncthreads();

    float acc[NPB];
#pragma unroll
    for (int r = 0; r < NPB; ++r) acc[r] = 2.0f;

    const unsigned int* cp = coefT + (long)i0 * OUT_ + tid;

#pragma unroll 4
    for (int ii = 0; ii < ISTEPS; ++ii) {
        unsigned int c = cp[(long)ii * OUT_];
        float a = __uint_as_float(c << 16);
        float b = __uint_as_float(c & 0xffff0000u);
        const float4* xv = (const float4*)&xT[ii * NPB];
        float4 x0 = xv[0];
        float4 x1 = xv[1];
        acc[0] = fminf(acc[0], fmaf(a, x0.x, b));
        acc[1] = fminf(acc[1], fmaf(a, x0.y, b));
        acc[2] = fminf(acc[2], fmaf(a, x0.z, b));
        acc[3] = fminf(acc[3], fmaf(a, x0.w, b));
        acc[4] = fminf(acc[4], fmaf(a, x1.x, b));
        acc[5] = fminf(acc[5], fmaf(a, x1.y, b));
        acc[6] = fminf(acc[6], fmaf(a, x1.z, b));
        acc[7] = fminf(acc[7], fmaf(a, x1.w, b));
    }

    if (write_final) {
        float s = signv[tid];
#pragma unroll
        for (int r = 0; r < NPB; ++r)
            outp[(n0 + r) * OUT_ + tid] = s * acc[r];
    } else {
#pragma unroll
        for (int r = 0; r < NPB; ++r)
            outp[((long)ks * N_ + (n0 + r)) * OUT_ + tid] = acc[r];
    }
}

// ---------------------------------------------------------------------------
// Kernel D: combine I-chunk partials and apply the sign.
// ---------------------------------------------------------------------------
__global__ __launch_bounds__(256) void reduce_kernel(
        const float* __restrict__ partial,   // [NSPLIT, N, OUT]
        const float* __restrict__ signv,
        float* __restrict__ out,             // [N, OUT]
        int nsplit) {
    int j = blockIdx.x * 256 + threadIdx.x;  // < N_*OUT_
    float m = partial[j];
    for (int k = 1; k < nsplit; ++k)
        m = fminf(m, partial[(long)k * (N_ * OUT_) + j]);
    out[j] = signv[j & (OUT_ - 1)] * m;
}

extern "C" void kernel_launch(void* const* d_in, const int* in_sizes, int n_in,
                              void* d_out, int out_size, void* d_ws, size_t ws_size,
                              hipStream_t stream) {
    const float* x           = (const float*)d_in[0];
    const float* edge_logits = (const float*)d_in[1];
    const float* op_logits   = (const float*)d_in[2];
    const float* u_edge      = (const float*)d_in[3];
    const float* u_op        = (const float*)d_in[4];
    float* out = (float*)d_out;

    char* ws = (char*)d_ws;
    int*   opidx   = (int*)(ws);
    float* signv   = (float*)(ws + 1024);
    float* neutral = (float*)(ws + 2048);
    unsigned int* coefT = (unsigned int*)(ws + 4096);
    float* partial = (float*)(ws + 4096 + (size_t)IN_ * OUT_ * 4);

    setup_op_kernel<<<1, 256, 0, stream>>>(op_logits, u_op, opidx, signv, neutral);
    setup_coef_kernel<<<IN_, 256, 0, stream>>>(edge_logits, u_edge, opidx, signv,
                                               neutral, coefT);

    size_t need = 4096 + (size_t)IN_ * OUT_ * 4 + 4ull * N_ * OUT_ * 4;
    if (ws_size >= need) {
        // 4 I-chunks x 128 n-tiles = 512 blocks (2 per CU)
        main_kernel<8, 128><<<(N_ / 8) * 4, 256, 0, stream>>>(x, coefT, signv,
                                                              partial, 0);
        reduce_kernel<<<(N_ * OUT_) / 256, 256, 0, stream>>>(partial, signv, out, 4);
    } else {
        // fallback: no I-split, write final directly (128 blocks)
        main_kernel<8, 512><<<(N_ / 8), 256, 0, stream>>>(x, coefT, signv, out, 1);
    }
}